// Round 1
// baseline (4960.432 us; speedup 1.0000x reference)
//
#include <hip/hip_runtime.h>
#include <hip/hip_fp16.h>

// WFDSA: wavelet dual-branch cosine attention. B=2048, N=256, C=96, H=3, d=32.
// Workspace layout (302.1 MB total):
//   qn  : half [B][H][N][32]   = 100663296 B   (l2-normalized q)
//   knl : float[B][H][64][32]  =  50331648 B   (normalized low keys)
//   vl  : float[B][H][64][32]  =  50331648 B
//   knh : float[B][H][64][32]  =  50331648 B
//   vh  : float[B][H][64][32]  =  50331648 B
//   W2  : float[96][192]       =     73728 B   (proj_w @ fuse_lh_w folded)
//   b2  : float[96]            =       384 B

#define B_ 2048
#define N_ 256
#define C_ 96
#define H_ 3
#define D_ 32

typedef __half half_t;

// ---------------- K0: W2 = proj_w @ fuse_lh_w ; b2 = proj_w @ fuse_b + proj_b
__global__ __launch_bounds__(192) void wfdsa_k0(
    const float* __restrict__ proj_w, const float* __restrict__ proj_b,
    const float* __restrict__ fuse_w, const float* __restrict__ fuse_b,
    float* __restrict__ W2, float* __restrict__ b2)
{
  int c = blockIdx.x;      // 96 blocks
  int j = threadIdx.x;     // 192 threads
  float acc = 0.f;
  for (int m = 0; m < 96; ++m)
    acc = fmaf(proj_w[c*96 + m], fuse_w[m*192 + j], acc);
  W2[c*192 + j] = acc;
  if (j == 0) {
    float a2 = proj_b[c];
    for (int m = 0; m < 96; ++m) a2 = fmaf(proj_w[c*96 + m], fuse_b[m], a2);
    b2[c] = a2;
  }
}

// ---------------- K1: q = x @ q_w^T + q_b, per-head l2 norm -> qn (half)
// grid (B, 4): 64 rows per block. lane = row, wave-uniform cols -> scalar weight loads.
__global__ __launch_bounds__(256) void wfdsa_k1(
    const float* __restrict__ x, const float* __restrict__ qw,
    const float* __restrict__ qb, half_t* __restrict__ qn)
{
  __shared__ float xs[64*97];   // stride 97: conflict-free per-lane rows
  __shared__ float qs[64*97];
  __shared__ float nrm[192];
  const int tid = threadIdx.x;
  const int b = blockIdx.x;
  const int r0 = blockIdx.y * 64;
  const int lane = tid & 63;
  const int wv = __builtin_amdgcn_readfirstlane(tid >> 6);

  const float* xsrc = x + ((size_t)b*N_ + r0)*C_;
  for (int idx = tid; idx < 64*96; idx += 256)
    xs[(idx/96)*97 + (idx%96)] = xsrc[idx];
  __syncthreads();

  float acc[24];
  #pragma unroll
  for (int u = 0; u < 24; ++u) acc[u] = qb[wv*24 + u];
  for (int i = 0; i < 96; ++i) {
    float xv = xs[lane*97 + i];
    #pragma unroll
    for (int u = 0; u < 24; ++u)
      acc[u] = fmaf(xv, qw[(wv*24 + u)*96 + i], acc[u]);  // uniform -> s_load
  }
  #pragma unroll
  for (int u = 0; u < 24; ++u) qs[lane*97 + wv*24 + u] = acc[u];
  __syncthreads();

  if (tid < 192) {                 // 64 rows x 3 heads
    int r = tid/3, h = tid - 3*(tid/3);
    float ss = 0.f;
    #pragma unroll
    for (int dd = 0; dd < 32; ++dd) {
      float v = qs[r*97 + h*32 + dd];
      ss = fmaf(v, v, ss);
    }
    nrm[tid] = 1.f / fmaxf(sqrtf(ss), 1e-12f);
  }
  __syncthreads();

  for (int idx = tid; idx < 64*96; idx += 256) {
    int r = idx/96, o = idx%96;
    int h = o >> 5, dd = o & 31;
    qn[(((size_t)b*H_ + h)*N_ + r0 + r)*D_ + dd] =
        __float2half(qs[r*97 + o] * nrm[r*3 + h]);
  }
}

// ---------------- K2: per-batch NLWT -> (kv_low, conv+leaky -> kv_high)
// One block per batch. LDS: highs 36 KB (half) + 24 KB region (A_s+t_s, later xh_s).
__global__ __launch_bounds__(256) void wfdsa_k2(
    const float* __restrict__ x,
    const float* __restrict__ kvlw, const float* __restrict__ kvlb,
    const float* __restrict__ kvhw, const float* __restrict__ kvhb,
    const float* __restrict__ convw, const float* __restrict__ convb,
    float* __restrict__ knl, float* __restrict__ vl,
    float* __restrict__ knh, float* __restrict__ vh)
{
  __shared__ half_t highs[288*64];   // [sub*96 + c][pos], subs = Bh,Ch,Dh
  __shared__ float  region[6144];    // phase1-2: A_s half[6144] (12KB) + t_s float[1024] @+12KB
                                     // phase3-4: xh_s float[96*64]
  half_t* A_s = (half_t*)region;
  float*  t_s = region + 3072;
  float*  xh_s = region;

  const int tid = threadIdx.x;
  const int b = blockIdx.x;
  const int lane = tid & 63;
  const int wv = __builtin_amdgcn_readfirstlane(tid >> 6);
  const int yy = lane >> 3, xx = lane & 7;

  // ---- Phase 1: NLWT (each wave owns one channel per chunk) ----
  const float* xb = x + (size_t)b*N_*C_;
  for (int cg = 0; cg < 24; ++cg) {
    int c = cg*4 + wv;
    int n00 = yy*32 + xx*2;                       // (2yy)*16 + 2xx
    float x00 = xb[(size_t)n00*96 + c];
    float x01 = xb[(size_t)(n00+1)*96 + c];
    float x10 = xb[(size_t)(n00+16)*96 + c];
    float x11 = xb[(size_t)(n00+17)*96 + c];
    // t = U1 @ [x00,x01,x10,x11]
    float t0 =  0.8664f*x00 + 0.1026f*x01 + 0.4852f*x10 - 0.0574f*x11;
    float t1 = -0.1026f*x00 + 0.8664f*x01 - 0.0574f*x10 - 0.4852f*x11;
    float t2 =  0.4852f*x00 + 0.0574f*x01 - 0.8664f*x10 + 0.1026f*x11;
    float t3 =  0.0574f*x00 - 0.4852f*x01 - 0.1026f*x10 - 0.8664f*x11;
    t_s[wv*256 + lane]        = t0;
    t_s[wv*256 + 64 + lane]   = t1;
    t_s[wv*256 + 128 + lane]  = t2;
    t_s[wv*256 + 192 + lane]  = t3;
    __syncthreads();
    int yp = ((yy+1)&7)*8, xp = (xx+1)&7;         // rolls
    float a0 = t_s[wv*256 + yy*8 + xx];
    float a1 = t_s[wv*256 + 64 + yp + xx];
    float a2 = t_s[wv*256 + 128 + yy*8 + xp];
    float a3 = t_s[wv*256 + 192 + yp + xp];
    // subbands = U2 @ [a0,a1,a2,a3]
    float sA =  1.3968f*a0 + 0.2212f*a1 - 0.2212f*a2 - 1.3968f*a3;
    float sB = -0.2212f*a0 + 1.3968f*a1 - 1.3968f*a2 + 0.2212f*a3;
    float sC = -0.5412f*a0 - 1.3066f*a1 - 1.3066f*a2 - 0.5412f*a3;
    float sD =  1.3066f*a0 - 0.5412f*a1 - 0.5412f*a2 + 1.3066f*a3;
    A_s[c*64 + lane]            = __float2half(sA);
    highs[c*64 + lane]          = __float2half(sB);
    highs[(96 + c)*64 + lane]   = __float2half(sC);
    highs[(192 + c)*64 + lane]  = __float2half(sD);
    __syncthreads();
  }

  // ---- Phase 2: kv_low (wave = head, lane = position) ----
  if (wv < 3) {
    const int h = wv, pos = lane;
    float accK[32], accV[32];
    #pragma unroll
    for (int dd = 0; dd < 32; ++dd) {
      accK[dd] = kvlb[h*32 + dd];
      accV[dd] = kvlb[96 + h*32 + dd];
    }
    for (int c = 0; c < 96; ++c) {
      float av = __half2float(A_s[c*64 + pos]);
      const float* wk  = kvlw + (size_t)(h*32)*96 + c;       // uniform rows
      const float* wvp = kvlw + (size_t)(96 + h*32)*96 + c;
      #pragma unroll
      for (int dd = 0; dd < 32; ++dd) {
        accK[dd] = fmaf(av, wk[(size_t)dd*96], accK[dd]);
        accV[dd] = fmaf(av, wvp[(size_t)dd*96], accV[dd]);
      }
    }
    float ss = 0.f;
    #pragma unroll
    for (int dd = 0; dd < 32; ++dd) ss = fmaf(accK[dd], accK[dd], ss);
    float sc = 1.f / fmaxf(sqrtf(ss), 1e-12f);
    float* ko = knl + (((size_t)b*H_ + h)*64 + pos)*D_;
    float* vo = vl  + (((size_t)b*H_ + h)*64 + pos)*D_;
    #pragma unroll
    for (int dd = 0; dd < 32; ++dd) { ko[dd] = accK[dd]*sc; vo[dd] = accV[dd]; }
  }
  __syncthreads();   // A_s/t_s dead; region becomes xh_s

  // ---- Phase 3: 3x3 SAME conv (288->96) + LeakyReLU(0.2) ----
  {
    float msk[9]; int off[9];
    #pragma unroll
    for (int t9 = 0; t9 < 9; ++t9) {
      int ky = t9/3 - 1, kx = t9 - (t9/3)*3 - 1;
      int ny = yy + ky, nx = xx + kx;
      bool ok = ((unsigned)ny < 8u) && ((unsigned)nx < 8u);
      msk[t9] = ok ? 1.f : 0.f;
      off[t9] = ok ? ny*8 + nx : 0;
    }
    for (int g = 0; g < 3; ++g) {
      const int co0 = wv*24 + g*8;       // wave owns 24 out-channels, 8 at a time
      float acc[8];
      #pragma unroll
      for (int u = 0; u < 8; ++u) acc[u] = convb[co0 + u];
      for (int ci = 0; ci < 288; ++ci) {
        float hv[9];
        #pragma unroll
        for (int t9 = 0; t9 < 9; ++t9)
          hv[t9] = msk[t9] * __half2float(highs[ci*64 + off[t9]]);
        const float* wr = convw + ((size_t)co0*288 + ci)*9;   // uniform -> s_load
        #pragma unroll
        for (int u = 0; u < 8; ++u) {
          #pragma unroll
          for (int t9 = 0; t9 < 9; ++t9)
            acc[u] = fmaf(hv[t9], wr[(size_t)u*2592 + t9], acc[u]);
        }
      }
      #pragma unroll
      for (int u = 0; u < 8; ++u) {
        float v = acc[u];
        xh_s[(co0 + u)*64 + lane] = (v >= 0.f) ? v : 0.2f*v;
      }
    }
  }
  __syncthreads();

  // ---- Phase 4: kv_high ----
  if (wv < 3) {
    const int h = wv, pos = lane;
    float accK[32], accV[32];
    #pragma unroll
    for (int dd = 0; dd < 32; ++dd) {
      accK[dd] = kvhb[h*32 + dd];
      accV[dd] = kvhb[96 + h*32 + dd];
    }
    for (int c = 0; c < 96; ++c) {
      float av = xh_s[c*64 + pos];
      const float* wk  = kvhw + (size_t)(h*32)*96 + c;
      const float* wvp = kvhw + (size_t)(96 + h*32)*96 + c;
      #pragma unroll
      for (int dd = 0; dd < 32; ++dd) {
        accK[dd] = fmaf(av, wk[(size_t)dd*96], accK[dd]);
        accV[dd] = fmaf(av, wvp[(size_t)dd*96], accV[dd]);
      }
    }
    float ss = 0.f;
    #pragma unroll
    for (int dd = 0; dd < 32; ++dd) ss = fmaf(accK[dd], accK[dd], ss);
    float sc = 1.f / fmaxf(sqrtf(ss), 1e-12f);
    float* ko = knh + (((size_t)b*H_ + h)*64 + pos)*D_;
    float* vo = vh  + (((size_t)b*H_ + h)*64 + pos)*D_;
    #pragma unroll
    for (int dd = 0; dd < 32; ++dd) { ko[dd] = accK[dd]*sc; vo[dd] = accV[dd]; }
  }
}

// ---------------- K3: dual-branch attention + folded fuse/proj GEMM
// grid (B, 4): 64 q-rows per block. lane = row; waves split keys/dd/out-cols.
__global__ __launch_bounds__(256) void wfdsa_k3(
    const half_t* __restrict__ qn,
    const float* __restrict__ knl, const float* __restrict__ vl,
    const float* __restrict__ knh, const float* __restrict__ vh,
    const float* __restrict__ W2, const float* __restrict__ b2,
    const float* __restrict__ lsl, const float* __restrict__ lsh,
    float* __restrict__ out)
{
  __shared__ float out_s[64*97];     // padded: lane-major conflict-free
  __shared__ float logit_s[64*65];
  __shared__ float a_s[64*33];
  const int tid = threadIdx.x;
  const int b = blockIdx.x;
  const int r0 = blockIdx.y * 64;
  const int lane = tid & 63;
  const int wv = __builtin_amdgcn_readfirstlane(tid >> 6);

  for (int idx = tid; idx < 64*96; idx += 256)
    out_s[(idx/96)*97 + (idx%96)] = b2[idx%96];

  const float LOG100 = 4.605170185988091f;
  for (int h = 0; h < 3; ++h) {
    float q[32];
    const half_t* qp = qn + (((size_t)b*H_ + h)*N_ + r0 + lane)*D_;
    #pragma unroll
    for (int dd = 0; dd < 32; ++dd) q[dd] = __half2float(qp[dd]);
    for (int br = 0; br < 2; ++br) {
      const float* kn = (br ? knh : knl) + (((size_t)b*H_ + h)*64)*D_;
      const float* vv = (br ? vh  : vl ) + (((size_t)b*H_ + h)*64)*D_;
      float sc = __expf(fminf((br ? lsh : lsl)[h], LOG100));
      __syncthreads();
      // A: logits, wave wv computes keys [wv*16, wv*16+16)
      for (int kk = 0; kk < 16; ++kk) {
        int k = wv*16 + kk;
        const float* kr = kn + k*32;         // uniform -> s_load row
        float acc = 0.f;
        #pragma unroll
        for (int dd = 0; dd < 32; ++dd) acc = fmaf(q[dd], kr[dd], acc);
        logit_s[lane*65 + k] = acc * sc;
      }
      __syncthreads();
      // B: per-row softmax stats (each wave duplicates) + PV for dd chunk wv*8..+8
      float m = -1e30f;
      for (int k = 0; k < 64; ++k) m = fmaxf(m, logit_s[lane*65 + k]);
      float s = 0.f;
      for (int k = 0; k < 64; ++k) s += __expf(logit_s[lane*65 + k] - m);
      float rs = 1.f / s;
      float o8[8];
      #pragma unroll
      for (int j = 0; j < 8; ++j) o8[j] = 0.f;
      for (int k = 0; k < 64; ++k) {
        float wgt = __expf(logit_s[lane*65 + k] - m) * rs;
        const float* vr = vv + k*32 + wv*8;  // uniform -> s_load chunk
        #pragma unroll
        for (int j = 0; j < 8; ++j) o8[j] = fmaf(wgt, vr[j], o8[j]);
      }
      #pragma unroll
      for (int j = 0; j < 8; ++j) a_s[lane*33 + wv*8 + j] = o8[j];
      __syncthreads();
      // C: out[r][c] += sum_dd a[r][dd] * W2[c][br*96 + dd*3 + h]
      float a[32];
      #pragma unroll
      for (int dd = 0; dd < 32; ++dd) a[dd] = a_s[lane*33 + dd];
      for (int u = 0; u < 24; ++u) {
        int c = wv*24 + u;
        const float* wr = W2 + (size_t)c*192 + br*96 + h;   // uniform -> s_load
        float acc = 0.f;
        #pragma unroll
        for (int dd = 0; dd < 32; ++dd) acc = fmaf(a[dd], wr[dd*3], acc);
        out_s[lane*97 + c] += acc;
      }
    }
  }
  __syncthreads();
  float* op = out + ((size_t)b*N_ + r0)*C_;
  for (int idx = tid; idx < 64*96; idx += 256)
    op[idx] = out_s[(idx/96)*97 + (idx%96)];
}

extern "C" void kernel_launch(void* const* d_in, const int* in_sizes, int n_in,
                              void* d_out, int out_size, void* d_ws, size_t ws_size,
                              hipStream_t stream)
{
  const float* x     = (const float*)d_in[0];
  const float* q_w   = (const float*)d_in[1];
  const float* q_b   = (const float*)d_in[2];
  const float* kvlw  = (const float*)d_in[3];
  const float* kvlb  = (const float*)d_in[4];
  const float* kvhw  = (const float*)d_in[5];
  const float* kvhb  = (const float*)d_in[6];
  const float* convw = (const float*)d_in[7];
  const float* convb = (const float*)d_in[8];
  const float* fusew = (const float*)d_in[9];
  const float* fuseb = (const float*)d_in[10];
  const float* projw = (const float*)d_in[11];
  const float* projb = (const float*)d_in[12];
  const float* lsl   = (const float*)d_in[13];
  const float* lsh   = (const float*)d_in[14];
  float* out = (float*)d_out;

  char* ws = (char*)d_ws;
  half_t* qn = (half_t*)ws;  ws += (size_t)B_*H_*N_*D_*sizeof(half_t);
  float* knl = (float*)ws;   ws += (size_t)B_*H_*64*D_*sizeof(float);
  float* vl  = (float*)ws;   ws += (size_t)B_*H_*64*D_*sizeof(float);
  float* knh = (float*)ws;   ws += (size_t)B_*H_*64*D_*sizeof(float);
  float* vh  = (float*)ws;   ws += (size_t)B_*H_*64*D_*sizeof(float);
  float* W2  = (float*)ws;   ws += (size_t)96*192*sizeof(float);
  float* b2  = (float*)ws;   ws += (size_t)96*sizeof(float);
  // total used: ~302.1 MB of d_ws

  wfdsa_k0<<<96, 192, 0, stream>>>(projw, projb, fusew, fuseb, W2, b2);
  wfdsa_k1<<<dim3(B_, 4), 256, 0, stream>>>(x, q_w, q_b, qn);
  wfdsa_k2<<<B_, 256, 0, stream>>>(x, kvlw, kvlb, kvhw, kvhb, convw, convb,
                                   knl, vl, knh, vh);
  wfdsa_k3<<<dim3(B_, 4), 256, 0, stream>>>(qn, knl, vl, knh, vh, W2, b2,
                                            lsl, lsh, out);
}